// Round 8
// baseline (276.630 us; speedup 1.0000x reference)
//
#include <hip/hip_runtime.h>
#include <hip/hip_bf16.h>
#include <math.h>

typedef unsigned short u16;
typedef float float4e __attribute__((ext_vector_type(4)));
typedef short short8 __attribute__((ext_vector_type(8)));
typedef unsigned short ushort8 __attribute__((ext_vector_type(8)));
typedef unsigned short u16x4 __attribute__((ext_vector_type(4)));

#define SEQ 2048
#define DIM 512
#define NB  4

// counted waitcnt + raw barrier (no compiler-forced vmcnt(0) drain)
#define VMCNT(n) asm volatile("s_waitcnt vmcnt(" #n ")" ::: "memory")
#define BAR() __builtin_amdgcn_s_barrier()

__device__ __forceinline__ float bf2f(u16 h) {
    return __uint_as_float(((unsigned)h) << 16);
}
__device__ __forceinline__ u16 f2bf(float f) {
    __hip_bfloat16 h = __float2bfloat16(f);
    return *reinterpret_cast<u16*>(&h);
}
__device__ __forceinline__ float curv_of(float raw) {
    return -2.0f + 2.0f * (tanhf(raw) + 1.0f);   // bounds (-2,2)
}
// async global->LDS, 16B per lane; lds base wave-uniform (lane lands at base+lane*16)
__device__ __forceinline__ void gl_lds16(const u16* g, u16* lds) {
    __builtin_amdgcn_global_load_lds(
        (const __attribute__((address_space(1))) unsigned int*)g,
        (__attribute__((address_space(3))) unsigned int*)lds, 16, 0, 0);
}

// ---------------- fused conversions + zero lsum/qn2r/kn2r ----------------
__global__ __launch_bounds__(256) void cvt_all_kernel(
    const float* __restrict__ x, const float* __restrict__ Wq,
    const float* __restrict__ Wk, const float* __restrict__ Wv,
    u16* __restrict__ x_bf, u16* __restrict__ Wcat,
    float* __restrict__ lsum, float* __restrict__ qn2r, float* __restrict__ kn2r)
{
    const int n_x = NB * SEQ * DIM, n_w = DIM * DIM;
    int gid = blockIdx.x * 256 + threadIdx.x;
    if (gid < NB * SEQ) { lsum[gid] = 0.f; qn2r[gid] = 0.f; kn2r[gid] = 0.f; }
    int i4 = gid * 4;
    if (i4 < n_x) {
        float4 v = *(const float4*)&x[i4];
        u16x4 h = {f2bf(v.x), f2bf(v.y), f2bf(v.z), f2bf(v.w)};
        *(u16x4*)&x_bf[i4] = h;
    } else if (i4 < n_x + 3 * n_w) {
        int j = i4 - n_x;
        const float* W = (j < n_w) ? Wq : (j < 2 * n_w ? Wk : Wv);
        int off = j % n_w;
        float4 v = *(const float4*)&W[off];
        u16x4 h = {f2bf(v.x), f2bf(v.y), f2bf(v.z), f2bf(v.w)};
        *(u16x4*)&Wcat[j] = h;
    }
}

// =====================================================================
// QKV GEMM: 128x128-tile, BK=64, DOUBLE-BUFFERED with counted vmcnt(8)
// + raw s_barrier (next-tile gl_lds stay in flight across the barrier;
// never drain to 0 in the loop). XCD-swizzled flat grid.
// Outputs: qbuf/kbuf (bf16, +bias), vT[b][d][s]; atomicAdds raw row-norms.
// =====================================================================
__global__ __launch_bounds__(256, 2) void gemm_qkv_kernel(
    const u16* __restrict__ A, const u16* __restrict__ Bt,
    u16* __restrict__ qbuf, u16* __restrict__ kbuf, u16* __restrict__ vT,
    const float* __restrict__ bq, const float* __restrict__ bk, const float* __restrict__ bv,
    float* __restrict__ qn2r, float* __restrict__ kn2r)
{
    const int lda = 512, ldb = 512;
    // flat grid 768: xcd = n&7, i = n>>3 in [0,96): bn = i%12, bm = xcd + 8*(i/12)
    int n = blockIdx.x;
    int xcd = n & 7, i = n >> 3;
    int bn = i % 12, bm = xcd + 8 * (i / 12);

    __shared__ __align__(16) u16 As[2][128 * 64];
    __shared__ __align__(16) u16 Bs[2][128 * 64];

    int t = threadIdx.x, wave = t >> 6, lane = t & 63;
    int wr = wave >> 1, wc = wave & 1;
    int lrow = lane & 15, quad = lane >> 4;
    int srow = lane >> 3, sc8 = lane & 7;

    const u16* Ab = A + (size_t)(bm * 128) * lda;
    const u16* Bb = Bt + (size_t)(bn * 128) * ldb;

    auto stage = [&](int buf, int kt) {   // 8 gl_lds per thread
        int k0 = kt << 6;
#pragma unroll
        for (int h = 0; h < 4; ++h) {
            int q = wave * 4 + h;
            int row = q * 8 + srow;
            int c = sc8 ^ (row & 7);
            gl_lds16(Ab + (size_t)row * lda + k0 + c * 8, &As[buf][q * 512]);
            gl_lds16(Bb + (size_t)row * ldb + k0 + c * 8, &Bs[buf][q * 512]);
        }
    };

    float4e acc[4][4];
#pragma unroll
    for (int i2 = 0; i2 < 4; i2++)
#pragma unroll
        for (int j = 0; j < 4; j++) acc[i2][j] = (float4e){0.f, 0.f, 0.f, 0.f};

    stage(0, 0);
    for (int kt = 0; kt < 8; ++kt) {
        int cur = kt & 1;
        if (kt + 1 < 8) { stage(cur ^ 1, kt + 1); VMCNT(8); }
        else            { VMCNT(0); }
        BAR();   // all waves' cur-tile loads landed
#pragma unroll
        for (int kk = 0; kk < 2; ++kk) {
            short8 af[4], bfr[4];
#pragma unroll
            for (int im = 0; im < 4; im++) {
                int R = wr * 64 + im * 16 + lrow;
                af[im] = *(const short8*)&As[cur][R * 64 + (((kk * 4 + quad) ^ (R & 7)) * 8)];
            }
#pragma unroll
            for (int in = 0; in < 4; in++) {
                int R = wc * 64 + in * 16 + lrow;
                bfr[in] = *(const short8*)&Bs[cur][R * 64 + (((kk * 4 + quad) ^ (R & 7)) * 8)];
            }
#pragma unroll
            for (int im = 0; im < 4; im++)
#pragma unroll
                for (int in = 0; in < 4; in++)
                    acc[im][in] = __builtin_amdgcn_mfma_f32_16x16x32_bf16(af[im], bfr[in], acc[im][in], 0, 0, 0);
        }
        BAR();   // all waves done reading cur -> safe to overwrite next iter
    }

    // epilogue — region is uniform per block (regions are 512-aligned, tiles 128)
    int region = bn >> 2;   // 0:q  1:k  2:v
    float nsum[4][4];
#pragma unroll
    for (int im = 0; im < 4; im++)
#pragma unroll
        for (int r = 0; r < 4; r++) nsum[im][r] = 0.f;

#pragma unroll
    for (int in = 0; in < 4; in++) {
        int gj = bn * 128 + wc * 64 + in * 16 + lrow;
        float bias = (gj < 512) ? bq[gj] : (gj < 1024 ? bk[gj - 512] : bv[gj - 1024]);
#pragma unroll
        for (int im = 0; im < 4; im++) {
            int gi0 = bm * 128 + wr * 64 + im * 16 + quad * 4;
            u16x4 pack;
#pragma unroll
            for (int r = 0; r < 4; r++) {
                u16 hv = f2bf(acc[im][in][r] + bias);
                pack[r] = hv;
                if (region == 0) {
                    qbuf[(size_t)(gi0 + r) * 512 + gj] = hv;
                } else if (region == 1) {
                    kbuf[(size_t)(gi0 + r) * 512 + (gj - 512)] = hv;
                }
                if (region < 2) { float vv = bf2f(hv); nsum[im][r] += vv * vv; }
            }
            if (region == 2) {   // vT[b][d][s], 4 consecutive s -> 8B store
                int bb = gi0 >> 11, s = gi0 & 2047;
                *(u16x4*)&vT[((size_t)bb * DIM + (gj - 1024)) * SEQ + s] = pack;
            }
        }
    }
    if (region < 2) {
        float* nrm = (region == 0) ? qn2r : kn2r;
#pragma unroll
        for (int im = 0; im < 4; im++)
#pragma unroll
            for (int r = 0; r < 4; r++) {
                float v = nsum[im][r];
                v += __shfl_xor(v, 1);
                v += __shfl_xor(v, 2);
                v += __shfl_xor(v, 4);
                v += __shfl_xor(v, 8);
                if (lrow == 0)
                    atomicAdd(&nrm[bm * 128 + wr * 64 + im * 16 + quad * 4 + r], v);
            }
    }
}

// =====================================================================
// Row projection scales: per row precompute {projected_norm^2, scale}.
// =====================================================================
__global__ __launch_bounds__(256) void rownorm_kernel(
    const float* __restrict__ qn2r, const float* __restrict__ kn2r,
    float2* __restrict__ qpk, float2* __restrict__ kpk,
    const float* __restrict__ curvp)
{
    int i = blockIdx.x * 256 + threadIdx.x;   // [0, 8192)
    float kv = curv_of(curvp[0]);
    float absk = fabsf(kv);
    float sk = sqrtf(fmaxf(absk, 1e-5f));
    bool euc = (absk < 0.01f);
    float mxn = (1.0f - 1e-3f) / sk;

    float qr = qn2r[i];
    float nq = sqrtf(qr + 1e-12f);
    float sq_ = euc ? 1.f : (kv < 0.f ? fminf(1.f, mxn / nq) : 1.f / (nq * sk));
    qpk[i] = make_float2(qr * sq_ * sq_, sq_);

    float kr = kn2r[i];
    float nk = sqrtf(kr + 1e-12f);
    float sk_ = euc ? 1.f : (kv < 0.f ? fminf(1.f, mxn / nk) : 1.f / (nk * sk));
    kpk[i] = make_float2(kr * sk_ * sk_, sk_);
}

// =====================================================================
// Scores GEMM: 128x128-tile, DOUBLE-BUFFERED counted-vmcnt 2-phase,
// XCD-swizzled flat grid. Epilogue: precomputed {norm^2, scale} float2
// loads + dist + exp2 + lsum atomics.
// =====================================================================
__global__ __launch_bounds__(256, 2) void gemm_scores_kernel(
    const u16* __restrict__ qbuf, const u16* __restrict__ kbuf,
    u16* __restrict__ attnH, float* __restrict__ lsum,
    const float2* __restrict__ qpk, const float2* __restrict__ kpk,
    const float* __restrict__ curvp, const float* __restrict__ tempp)
{
    const int lda = 512, ldb = 512, ldc = SEQ;
    // flat grid 1024: xcd = n&7, i = n>>3 in [0,128): bn = i&15,
    // strip = xcd + 8*(i>>4) in [0,64): bm = strip%16, b = strip/16
    int n = blockIdx.x;
    int xcd = n & 7, i = n >> 3;
    int bn = i & 15;
    int strip = xcd + 8 * (i >> 4);
    int bm = strip & 15, b = strip >> 4;
    if (bn > bm) return;   // fully-masked 128x128 tile (before any barrier)

    __shared__ __align__(16) u16 As[2][128 * 64];
    __shared__ __align__(16) u16 Bs[2][128 * 64];

    int t = threadIdx.x, wave = t >> 6, lane = t & 63;
    int wr = wave >> 1, wc = wave & 1;
    int lrow = lane & 15, quad = lane >> 4;
    int srow = lane >> 3, sc8 = lane & 7;

    const u16* Ab = qbuf + (size_t)(b * SEQ + bm * 128) * lda;
    const u16* Bb = kbuf + (size_t)(b * SEQ + bn * 128) * ldb;

    auto stage = [&](int buf, int kt) {   // 8 gl_lds per thread
        int k0 = kt << 6;
#pragma unroll
        for (int h = 0; h < 4; ++h) {
            int q = wave * 4 + h;
            int row = q * 8 + srow;
            int c = sc8 ^ (row & 7);
            gl_lds16(Ab + (size_t)row * lda + k0 + c * 8, &As[buf][q * 512]);
            gl_lds16(Bb + (size_t)row * ldb + k0 + c * 8, &Bs[buf][q * 512]);
        }
    };

    float4e acc[4][4];
#pragma unroll
    for (int i2 = 0; i2 < 4; i2++)
#pragma unroll
        for (int j = 0; j < 4; j++) acc[i2][j] = (float4e){0.f, 0.f, 0.f, 0.f};

    stage(0, 0);
    for (int kt = 0; kt < 8; ++kt) {
        int cur = kt & 1;
        if (kt + 1 < 8) { stage(cur ^ 1, kt + 1); VMCNT(8); }
        else            { VMCNT(0); }
        BAR();
#pragma unroll
        for (int kk = 0; kk < 2; ++kk) {
            short8 af[4], bfr[4];
#pragma unroll
            for (int im = 0; im < 4; im++) {
                int R = wr * 64 + im * 16 + lrow;
                af[im] = *(const short8*)&As[cur][R * 64 + (((kk * 4 + quad) ^ (R & 7)) * 8)];
            }
#pragma unroll
            for (int in = 0; in < 4; in++) {
                int R = wc * 64 + in * 16 + lrow;
                bfr[in] = *(const short8*)&Bs[cur][R * 64 + (((kk * 4 + quad) ^ (R & 7)) * 8)];
            }
#pragma unroll
            for (int im = 0; im < 4; im++)
#pragma unroll
                for (int in = 0; in < 4; in++)
                    acc[im][in] = __builtin_amdgcn_mfma_f32_16x16x32_bf16(af[im], bfr[in], acc[im][in], 0, 0, 0);
        }
        BAR();
    }

    float kv = curv_of(curvp[0]);
    float absk = fabsf(kv);
    float sk = sqrtf(fmaxf(absk, 1e-5f));
    bool euc = (absk < 0.01f);
    float invT = 1.0f / (tempp[0] + 1e-8f);
    float Cexp = -1.4426950408889634f * invT;        // e = exp2(dist * Cexp)
    u16* Cb = attnH + (size_t)b * SEQ * SEQ;

    // per-column {projected norm^2, scale} — pure loads
    float2 kp[4];
#pragma unroll
    for (int in = 0; in < 4; in++)
        kp[in] = kpk[b * SEQ + bn * 128 + wc * 64 + in * 16 + lrow];

    float psum[4][4];
#pragma unroll
    for (int im = 0; im < 4; im++)
#pragma unroll
        for (int r = 0; r < 4; r++) psum[im][r] = 0.f;

#pragma unroll
    for (int im = 0; im < 4; im++) {
#pragma unroll
        for (int r = 0; r < 4; r++) {
            int gi = bm * 128 + wr * 64 + im * 16 + quad * 4 + r;
            float2 qp = qpk[b * SEQ + gi];
            float qn = qp.x;
#pragma unroll
            for (int in = 0; in < 4; in++) {
                int gj = bn * 128 + wc * 64 + in * 16 + lrow;
                float kn = kp[in].x;
                float dot = acc[im][in][r] * qp.y * kp[in].y;
                float diff2 = fmaxf(qn + kn - 2.f * dot, 0.f);
                float dist;
                if (euc) {
                    dist = sqrtf(diff2 + 1e-12f);
                } else if (kv < 0.f) {
                    float denom = fmaxf((1.f - absk * qn) * (1.f - absk * kn), 1e-5f);
                    float arg = fmaxf(1.f + 2.f * absk * diff2 / denom, 1.f + 1e-7f);
                    dist = acoshf(arg) / sk;
                } else {
                    float c = fminf(fmaxf(absk * dot, -1.f + 1e-7f), 1.f - 1e-7f);
                    dist = acosf(c) / sk;
                }
                float e = (gj <= gi) ? exp2f(dist * Cexp) : 0.f;   // scores<=0 -> no max shift
                Cb[(size_t)gi * ldc + gj] = f2bf(e);
                psum[im][r] += e;
            }
        }
    }
#pragma unroll
    for (int im = 0; im < 4; im++)
#pragma unroll
        for (int r = 0; r < 4; r++) {
            float v = psum[im][r];
            v += __shfl_xor(v, 1);
            v += __shfl_xor(v, 2);
            v += __shfl_xor(v, 4);
            v += __shfl_xor(v, 8);
            if (lrow == 0) {
                int gi = bm * 128 + wr * 64 + im * 16 + quad * 4 + r;
                atomicAdd(&lsum[b * SEQ + gi], v);
            }
        }
}

// =====================================================================
// PV GEMM: 64x64, BK=64, DOUBLE-BUFFERED counted-vmcnt 2-phase, full
// causal K per block, XCD-swizzled flat grid. Direct fp32 store with
// 1/l + FUSED attnF emission (unique writer bn==kt%8; reads LDS between
// MFMA and the WAR barrier).
// =====================================================================
__global__ __launch_bounds__(256, 4) void gemm_pv_kernel(
    const u16* __restrict__ attnH, const u16* __restrict__ vT,
    float* __restrict__ out, float* __restrict__ attnF,
    const float* __restrict__ lsum)
{
    const int lda = SEQ, ldb = SEQ, ldc = DIM;
    // flat grid 1024: xcd = n&7, i = n>>3 in [0,128): bn = i&7,
    // strip = xcd + 8*(i>>3) in [0,128): bm = strip%32, b = strip/32
    int n = blockIdx.x;
    int xcd = n & 7, i = n >> 3;
    int bn = i & 7;
    int strip = xcd + 8 * (i >> 3);
    int bm = strip & 31, b = strip >> 5;

    __shared__ __align__(16) u16 As[2][64 * 64];
    __shared__ __align__(16) u16 Bs[2][64 * 64];

    int t = threadIdx.x, wave = t >> 6, lane = t & 63;
    int wr = wave >> 1, wc = wave & 1;
    int lrow = lane & 15, quad = lane >> 4;
    int srow = lane >> 3, sc = lane & 7;

    const u16* Ab = attnH + (size_t)b * SEQ * SEQ + (size_t)(bm * 64) * lda;
    const u16* Bb = vT + (size_t)b * DIM * SEQ + (size_t)(bn * 64) * ldb;
    float* attnFb = attnF + (size_t)b * SEQ * SEQ;

    // zero-fill the fully-masked attnF tiles owned by this bn
    {
        int r = t >> 2, c4 = t & 3;
        float4 z = (float4){0.f, 0.f, 0.f, 0.f};
        for (int kt = bm + 1; kt < 32; ++kt)
            if ((kt & 7) == bn) {
                float* dst = attnFb + (size_t)(bm * 64 + r) * SEQ + kt * 64 + c4 * 16;
                ((float4*)dst)[0] = z; ((float4*)dst)[1] = z;
                ((float4*)dst)[2] = z; ((float4*)dst)[3] = z;
            }
    }

    auto stage = [&](int buf, int kt) {   // 4 gl_lds per thread
        int k0 = kt << 6;
#pragma unroll
        for (int h = 0; h < 2; ++h) {
            int q = wave * 2 + h;
            int row = q * 8 + srow;
            int c = sc ^ (row & 7);
            gl_lds16(Ab + (size_t)row * lda + k0 + c * 8, &As[buf][q * 512]);
            gl_lds16(Bb + (size_t)row * ldb + k0 + c * 8, &Bs[buf][q * 512]);
        }
    };

    float4e acc[2][2];
#pragma unroll
    for (int i2 = 0; i2 < 2; i2++)
#pragma unroll
        for (int j = 0; j < 2; j++) acc[i2][j] = (float4e){0.f, 0.f, 0.f, 0.f};

    stage(0, 0);
    for (int kt = 0; kt <= bm; ++kt) {
        int cur = kt & 1;
        if (kt < bm) { stage(cur ^ 1, kt + 1); VMCNT(4); }
        else         { VMCNT(0); }
        BAR();
#pragma unroll
        for (int s = 0; s < 2; ++s) {
            short8 af[2], bfr[2];
#pragma unroll
            for (int im = 0; im < 2; im++) {
                int R = wr * 32 + im * 16 + lrow;
                af[im] = *(const short8*)&As[cur][R * 64 + (((s * 4 + quad) ^ (R & 7)) * 8)];
            }
#pragma unroll
            for (int in = 0; in < 2; in++) {
                int R = wc * 32 + in * 16 + lrow;
                bfr[in] = *(const short8*)&Bs[cur][R * 64 + (((s * 4 + quad) ^ (R & 7)) * 8)];
            }
#pragma unroll
            for (int im = 0; im < 2; im++)
#pragma unroll
                for (int in = 0; in < 2; in++)
                    acc[im][in] = __builtin_amdgcn_mfma_f32_16x16x32_bf16(af[im], bfr[in], acc[im][in], 0, 0, 0);
        }
        // fused attnF emission from the staged LDS A-tile (unique writer: bn == kt%8)
        if ((kt & 7) == bn) {
            int r = t >> 2, c4 = t & 3;
            int gi = bm * 64 + r;
            float invl = 1.0f / lsum[b * SEQ + gi];
            const u16* src = &As[cur][r * 64];
            int j0 = c4 * 2;
            ushort8 u0 = *(const ushort8*)&src[(j0 ^ (r & 7)) * 8];
            ushort8 u1 = *(const ushort8*)&src[((j0 + 1) ^ (r & 7)) * 8];
            float* dst = attnFb + (size_t)gi * SEQ + kt * 64 + c4 * 16;
            float4 f0 = {bf2f(u0[0]) * invl, bf2f(u0[1]) * invl, bf2f(u0[2]) * invl, bf2f(u0[3]) * invl};
            float4 f1 = {bf2f(u0[4]) * invl, bf2f(u0[5]) * invl, bf2f(u0[6]) * invl, bf2f(u0[7]) * invl};
            float4 f2 = {bf2f(u1[0]) * invl, bf2f(u1[1]) * invl, bf2f(u1[2]) * invl, bf2f(u1[3]) * invl};
            float4 f3 = {bf2f(u1[4]) * invl, bf2f(u1[5]) * invl, bf2f(u1[6]) * invl, bf2f(u1[7]) * invl};
            ((float4*)dst)[0] = f0; ((float4*)dst)[1] = f1;
            ((float4*)dst)[2] = f2; ((float4*)dst)[3] = f3;
        }
        BAR();   // WAR: safe to overwrite cur next iter
    }

    float* Cb = out + (size_t)b * SEQ * DIM;
#pragma unroll
    for (int im = 0; im < 2; im++)
#pragma unroll
        for (int r = 0; r < 4; r++) {
            int gi = bm * 64 + wr * 32 + im * 16 + quad * 4 + r;
            float invl = 1.0f / lsum[b * SEQ + gi];
#pragma unroll
            for (int in = 0; in < 2; in++) {
                int gd = bn * 64 + wc * 32 + in * 16 + lrow;
                Cb[(size_t)gi * ldc + gd] = acc[im][in][r] * invl;
            }
        }
}

// ---------------- launch ----------------
extern "C" void kernel_launch(void* const* d_in, const int* in_sizes, int n_in,
                              void* d_out, int out_size, void* d_ws, size_t ws_size,
                              hipStream_t stream) {
    (void)in_sizes; (void)n_in; (void)out_size; (void)ws_size;

    const float* x    = (const float*)d_in[0];
    const float* Wq   = (const float*)d_in[1];
    const float* bq   = (const float*)d_in[2];
    const float* Wk   = (const float*)d_in[3];
    const float* bk   = (const float*)d_in[4];
    const float* Wv   = (const float*)d_in[5];
    const float* bv   = (const float*)d_in[6];
    const float* curv = (const float*)d_in[7];
    const float* temp = (const float*)d_in[8];

    float* out   = (float*)d_out;                       // [4][2048][512]
    float* attnF = out + (size_t)NB * SEQ * DIM;        // [4][2048][2048]

    char* ws = (char*)d_ws;
    // layout (bytes), peak 58.95 MB:
    //   0        attnH  33,554,432  (aliases x_bf@0 (8.4M) + Wcat@8388608
    //                                (1.5M) — both dead after QKV)
    //   33554432 qbuf    8,388,608  [8192][512] bf16
    //   41943040 kbuf    8,388,608  [8192][512] bf16
    //   50331648 vT      8,388,608  [4][512][2048] bf16
    //   58720256 qn2r       32,768  raw row-norm sums (f32)
    //   58753024 kn2r       32,768
    //   58785792 lsum       32,768
    //   58818560 qpk        65,536  float2 {proj norm^2, scale}
    //   58884096 kpk        65,536
    u16*   x_bf  = (u16*)(ws + 0);
    u16*   Wcat  = (u16*)(ws + 8388608);
    u16*   attnH = (u16*)(ws + 0);
    u16*   qbuf  = (u16*)(ws + 33554432);
    u16*   kbuf  = (u16*)(ws + 41943040);
    u16*   vT    = (u16*)(ws + 50331648);
    float* qn2r  = (float*)(ws + 58720256);
    float* kn2r  = (float*)(ws + 58753024);
    float* lsum  = (float*)(ws + 58785792);
    float2* qpk  = (float2*)(ws + 58818560);
    float2* kpk  = (float2*)(ws + 58884096);

    // K0: conversions + zero lsum/qn2r/kn2r
    {
        int n_tot = (NB * SEQ * DIM + 3 * DIM * DIM) / 4;
        cvt_all_kernel<<<(n_tot + 255) / 256, 256, 0, stream>>>(
            x, Wq, Wk, Wv, x_bf, Wcat, lsum, qn2r, kn2r);
    }

    // K1: QKV GEMM (M=8192, N=1536, K=512), XCD-swizzled flat grid 768
    gemm_qkv_kernel<<<768, 256, 0, stream>>>(
        x_bf, Wcat, qbuf, kbuf, vT, bq, bk, bv, qn2r, kn2r);

    // K1.5: per-row projection scales
    rownorm_kernel<<<NB * SEQ / 256, 256, 0, stream>>>(qn2r, kn2r, qpk, kpk, curv);

    // K2: scores + dist + exp + row sums, XCD-swizzled flat grid 1024
    gemm_scores_kernel<<<1024, 256, 0, stream>>>(
        qbuf, kbuf, attnH, lsum, qpk, kpk, curv, temp);

    // K3: PV + fused attnF, XCD-swizzled flat grid 1024
    gemm_pv_kernel<<<1024, 256, 0, stream>>>(
        attnH, vT, out, attnF, lsum);
}

// Round 10
// 227.414 us; speedup vs baseline: 1.2164x; 1.2164x over previous
//
#include <hip/hip_runtime.h>
#include <hip/hip_bf16.h>
#include <math.h>

typedef unsigned short u16;
typedef float float4e __attribute__((ext_vector_type(4)));
typedef short short8 __attribute__((ext_vector_type(8)));
typedef unsigned short ushort8 __attribute__((ext_vector_type(8)));
typedef unsigned short u16x4 __attribute__((ext_vector_type(4)));

#define SEQ 2048
#define DIM 512
#define NB  4

__device__ __forceinline__ float bf2f(u16 h) {
    return __uint_as_float(((unsigned)h) << 16);
}
__device__ __forceinline__ u16 f2bf(float f) {
    __hip_bfloat16 h = __float2bfloat16(f);
    return *reinterpret_cast<u16*>(&h);
}
__device__ __forceinline__ float curv_of(float raw) {
    return -2.0f + 2.0f * (tanhf(raw) + 1.0f);   // bounds (-2,2)
}
// async global->LDS, 16B per lane; lds base wave-uniform (lane lands at base+lane*16)
__device__ __forceinline__ void gl_lds16(const u16* g, u16* lds) {
    __builtin_amdgcn_global_load_lds(
        (const __attribute__((address_space(1))) unsigned int*)g,
        (__attribute__((address_space(3))) unsigned int*)lds, 16, 0, 0);
}

// ---------------- fused conversions + zero lsum/qn2r/kn2r ----------------
__global__ __launch_bounds__(256) void cvt_all_kernel(
    const float* __restrict__ x, const float* __restrict__ Wq,
    const float* __restrict__ Wk, const float* __restrict__ Wv,
    u16* __restrict__ x_bf, u16* __restrict__ Wcat,
    float* __restrict__ lsum, float* __restrict__ qn2r, float* __restrict__ kn2r)
{
    const int n_x = NB * SEQ * DIM, n_w = DIM * DIM;
    int gid = blockIdx.x * 256 + threadIdx.x;
    if (gid < NB * SEQ) { lsum[gid] = 0.f; qn2r[gid] = 0.f; kn2r[gid] = 0.f; }
    int i4 = gid * 4;
    if (i4 < n_x) {
        float4 v = *(const float4*)&x[i4];
        u16x4 h = {f2bf(v.x), f2bf(v.y), f2bf(v.z), f2bf(v.w)};
        *(u16x4*)&x_bf[i4] = h;
    } else if (i4 < n_x + 3 * n_w) {
        int j = i4 - n_x;
        const float* W = (j < n_w) ? Wq : (j < 2 * n_w ? Wk : Wv);
        int off = j % n_w;
        float4 v = *(const float4*)&W[off];
        u16x4 h = {f2bf(v.x), f2bf(v.y), f2bf(v.z), f2bf(v.w)};
        *(u16x4*)&Wcat[j] = h;
    }
}

// =====================================================================
// QKV GEMM: 128x128-tile, BK=64, single-buffer gl_lds 2-barrier (the
// 234us-best structure, unchanged). XCD-swizzled flat grid 768.
// Outputs: qbuf/kbuf (bf16, +bias), vT[b][d][s]; atomicAdds raw row-norms.
// =====================================================================
__global__ __launch_bounds__(256, 2) void gemm_qkv_kernel(
    const u16* __restrict__ A, const u16* __restrict__ Bt,
    u16* __restrict__ qbuf, u16* __restrict__ kbuf, u16* __restrict__ vT,
    const float* __restrict__ bq, const float* __restrict__ bk, const float* __restrict__ bv,
    float* __restrict__ qn2r, float* __restrict__ kn2r)
{
    const int lda = 512, ldb = 512;
    // flat grid 768: xcd = n&7, i = n>>3 in [0,96): bn = i%12, bm = xcd + 8*(i/12)
    int n = blockIdx.x;
    int xcd = n & 7, i = n >> 3;
    int bn = i % 12, bm = xcd + 8 * (i / 12);

    __shared__ __align__(16) u16 As[128 * 64];
    __shared__ __align__(16) u16 Bs[128 * 64];

    int t = threadIdx.x, wave = t >> 6, lane = t & 63;
    int wr = wave >> 1, wc = wave & 1;
    int lrow = lane & 15, quad = lane >> 4;
    int srow = lane >> 3, sc8 = lane & 7;

    const u16* Ab = A + (size_t)(bm * 128) * lda;
    const u16* Bb = Bt + (size_t)(bn * 128) * ldb;

    float4e acc[4][4];
#pragma unroll
    for (int i2 = 0; i2 < 4; i2++)
#pragma unroll
        for (int j = 0; j < 4; j++) acc[i2][j] = (float4e){0.f, 0.f, 0.f, 0.f};

    for (int kt = 0; kt < 8; ++kt) {
        int k0 = kt << 6;
        __syncthreads();
#pragma unroll
        for (int h = 0; h < 4; ++h) {
            int q = wave * 4 + h;
            int row = q * 8 + srow;
            int c = sc8 ^ (row & 7);
            gl_lds16(Ab + (size_t)row * lda + k0 + c * 8, &As[q * 512]);
            gl_lds16(Bb + (size_t)row * ldb + k0 + c * 8, &Bs[q * 512]);
        }
        __syncthreads();
#pragma unroll
        for (int kk = 0; kk < 2; ++kk) {
            short8 af[4], bfr[4];
#pragma unroll
            for (int im = 0; im < 4; im++) {
                int R = wr * 64 + im * 16 + lrow;
                af[im] = *(const short8*)&As[R * 64 + (((kk * 4 + quad) ^ (R & 7)) * 8)];
            }
#pragma unroll
            for (int in = 0; in < 4; in++) {
                int R = wc * 64 + in * 16 + lrow;
                bfr[in] = *(const short8*)&Bs[R * 64 + (((kk * 4 + quad) ^ (R & 7)) * 8)];
            }
#pragma unroll
            for (int im = 0; im < 4; im++)
#pragma unroll
                for (int in = 0; in < 4; in++)
                    acc[im][in] = __builtin_amdgcn_mfma_f32_16x16x32_bf16(af[im], bfr[in], acc[im][in], 0, 0, 0);
        }
    }

    // epilogue — region is uniform per block (regions are 512-aligned, tiles 128)
    int region = bn >> 2;   // 0:q  1:k  2:v
    float nsum[4][4];
#pragma unroll
    for (int im = 0; im < 4; im++)
#pragma unroll
        for (int r = 0; r < 4; r++) nsum[im][r] = 0.f;

#pragma unroll
    for (int in = 0; in < 4; in++) {
        int gj = bn * 128 + wc * 64 + in * 16 + lrow;
        float bias = (gj < 512) ? bq[gj] : (gj < 1024 ? bk[gj - 512] : bv[gj - 1024]);
#pragma unroll
        for (int im = 0; im < 4; im++) {
            int gi0 = bm * 128 + wr * 64 + im * 16 + quad * 4;
            u16x4 pack;
#pragma unroll
            for (int r = 0; r < 4; r++) {
                u16 hv = f2bf(acc[im][in][r] + bias);
                pack[r] = hv;
                if (region == 0) {
                    qbuf[(size_t)(gi0 + r) * 512 + gj] = hv;
                } else if (region == 1) {
                    kbuf[(size_t)(gi0 + r) * 512 + (gj - 512)] = hv;
                }
                if (region < 2) { float vv = bf2f(hv); nsum[im][r] += vv * vv; }
            }
            if (region == 2) {   // vT[b][d][s], 4 consecutive s -> 8B store
                int bb = gi0 >> 11, s = gi0 & 2047;
                *(u16x4*)&vT[((size_t)bb * DIM + (gj - 1024)) * SEQ + s] = pack;
            }
        }
    }
    if (region < 2) {
        float* nrm = (region == 0) ? qn2r : kn2r;
#pragma unroll
        for (int im = 0; im < 4; im++)
#pragma unroll
            for (int r = 0; r < 4; r++) {
                float v = nsum[im][r];
                v += __shfl_xor(v, 1);
                v += __shfl_xor(v, 2);
                v += __shfl_xor(v, 4);
                v += __shfl_xor(v, 8);
                if (lrow == 0)
                    atomicAdd(&nrm[bm * 128 + wr * 64 + im * 16 + quad * 4 + r], v);
            }
    }
}

// =====================================================================
// Row projection scales: per row precompute {projected_norm^2, scale}.
// =====================================================================
__global__ __launch_bounds__(256) void rownorm_kernel(
    const float* __restrict__ qn2r, const float* __restrict__ kn2r,
    float2* __restrict__ qpk, float2* __restrict__ kpk,
    const float* __restrict__ curvp)
{
    int i = blockIdx.x * 256 + threadIdx.x;   // [0, 8192)
    float kv = curv_of(curvp[0]);
    float absk = fabsf(kv);
    float sk = sqrtf(fmaxf(absk, 1e-5f));
    bool euc = (absk < 0.01f);
    float mxn = (1.0f - 1e-3f) / sk;

    float qr = qn2r[i];
    float nq = sqrtf(qr + 1e-12f);
    float sq_ = euc ? 1.f : (kv < 0.f ? fminf(1.f, mxn / nq) : 1.f / (nq * sk));
    qpk[i] = make_float2(qr * sq_ * sq_, sq_);

    float kr = kn2r[i];
    float nk = sqrtf(kr + 1e-12f);
    float sk_ = euc ? 1.f : (kv < 0.f ? fminf(1.f, mxn / nk) : 1.f / (nk * sk));
    kpk[i] = make_float2(kr * sk_ * sk_, sk_);
}

// =====================================================================
// Scores GEMM: 128x128-tile, single-buffer 2-barrier, 512 THREADS /
// 8 WAVES per block (each wave owns 64x32, acc[4][2]) — grid is only
// ~2.1 active blocks/CU, so 8-wave blocks double resident waves/CU
// (8.5 -> ~17) in this latency-bound regime. Balanced causal XCD map:
// XCD x owns bm in {x, 15-x} per batch -> exactly 68 active blocks/XCD.
// Epilogue: precomputed {norm^2, scale} float2 loads + dist + exp2 + lsum.
// =====================================================================
__global__ __launch_bounds__(512, 4) void gemm_scores_kernel(
    const u16* __restrict__ qbuf, const u16* __restrict__ kbuf,
    u16* __restrict__ attnH, float* __restrict__ lsum,
    const float2* __restrict__ qpk, const float2* __restrict__ kpk,
    const float* __restrict__ curvp, const float* __restrict__ tempp)
{
    const int lda = 512, ldb = 512, ldc = SEQ;
    // flat grid 1024: xcd = n&7, i = n>>3 in [0,128): bn = i&15, j = i>>4:
    // b = j>>1, bm = (j&1) ? xcd : 15-xcd   (balanced: 17 active/batch/XCD)
    int n = blockIdx.x;
    int xcd = n & 7, i = n >> 3;
    int bn = i & 15;
    int j = i >> 4;
    int b = j >> 1;
    int bm = (j & 1) ? xcd : 15 - xcd;
    if (bn > bm) return;   // fully-masked 128x128 tile (before any barrier)

    __shared__ __align__(16) u16 As[128 * 64];
    __shared__ __align__(16) u16 Bs[128 * 64];

    int t = threadIdx.x, wave = t >> 6, lane = t & 63;
    int wr = wave >> 2, wc = wave & 3;        // 8 waves: 2 row-halves x 4 col-quarters
    int lrow = lane & 15, quad = lane >> 4;
    int srow = lane >> 3, sc8 = lane & 7;

    const u16* Ab = qbuf + (size_t)(b * SEQ + bm * 128) * lda;
    const u16* Bb = kbuf + (size_t)(b * SEQ + bn * 128) * ldb;

    float4e acc[4][2];
#pragma unroll
    for (int i2 = 0; i2 < 4; i2++)
#pragma unroll
        for (int j2 = 0; j2 < 2; j2++) acc[i2][j2] = (float4e){0.f, 0.f, 0.f, 0.f};

    for (int kt = 0; kt < 8; ++kt) {
        int k0 = kt << 6;
        __syncthreads();
#pragma unroll
        for (int h = 0; h < 2; ++h) {       // 8 waves x 2 calls cover 128 rows
            int q = wave * 2 + h;
            int row = q * 8 + srow;
            int c = sc8 ^ (row & 7);
            gl_lds16(Ab + (size_t)row * lda + k0 + c * 8, &As[q * 512]);
            gl_lds16(Bb + (size_t)row * ldb + k0 + c * 8, &Bs[q * 512]);
        }
        __syncthreads();
#pragma unroll
        for (int kk = 0; kk < 2; ++kk) {
            short8 af[4], bfr[2];
#pragma unroll
            for (int im = 0; im < 4; im++) {
                int R = wr * 64 + im * 16 + lrow;
                af[im] = *(const short8*)&As[R * 64 + (((kk * 4 + quad) ^ (R & 7)) * 8)];
            }
#pragma unroll
            for (int in = 0; in < 2; in++) {
                int R = wc * 32 + in * 16 + lrow;
                bfr[in] = *(const short8*)&Bs[R * 64 + (((kk * 4 + quad) ^ (R & 7)) * 8)];
            }
#pragma unroll
            for (int im = 0; im < 4; im++)
#pragma unroll
                for (int in = 0; in < 2; in++)
                    acc[im][in] = __builtin_amdgcn_mfma_f32_16x16x32_bf16(af[im], bfr[in], acc[im][in], 0, 0, 0);
        }
    }

    float kv = curv_of(curvp[0]);
    float absk = fabsf(kv);
    float sk = sqrtf(fmaxf(absk, 1e-5f));
    bool euc = (absk < 0.01f);
    float invT = 1.0f / (tempp[0] + 1e-8f);
    float Cexp = -1.4426950408889634f * invT;        // e = exp2(dist * Cexp)
    u16* Cb = attnH + (size_t)b * SEQ * SEQ;

    // per-column {projected norm^2, scale} — pure loads
    float2 kp[2];
#pragma unroll
    for (int in = 0; in < 2; in++)
        kp[in] = kpk[b * SEQ + bn * 128 + wc * 32 + in * 16 + lrow];

    float psum[4][4];
#pragma unroll
    for (int im = 0; im < 4; im++)
#pragma unroll
        for (int r = 0; r < 4; r++) psum[im][r] = 0.f;

#pragma unroll
    for (int im = 0; im < 4; im++) {
#pragma unroll
        for (int r = 0; r < 4; r++) {
            int gi = bm * 128 + wr * 64 + im * 16 + quad * 4 + r;
            float2 qp = qpk[b * SEQ + gi];
            float qn = qp.x;
#pragma unroll
            for (int in = 0; in < 2; in++) {
                int gj = bn * 128 + wc * 32 + in * 16 + lrow;
                float kn = kp[in].x;
                float dot = acc[im][in][r] * qp.y * kp[in].y;
                float diff2 = fmaxf(qn + kn - 2.f * dot, 0.f);
                float dist;
                if (euc) {
                    dist = sqrtf(diff2 + 1e-12f);
                } else if (kv < 0.f) {
                    float denom = fmaxf((1.f - absk * qn) * (1.f - absk * kn), 1e-5f);
                    float arg = fmaxf(1.f + 2.f * absk * diff2 / denom, 1.f + 1e-7f);
                    dist = acoshf(arg) / sk;
                } else {
                    float c = fminf(fmaxf(absk * dot, -1.f + 1e-7f), 1.f - 1e-7f);
                    dist = acosf(c) / sk;
                }
                float e = (gj <= gi) ? exp2f(dist * Cexp) : 0.f;   // scores<=0 -> no max shift
                Cb[(size_t)gi * ldc + gj] = f2bf(e);
                psum[im][r] += e;
            }
        }
    }
#pragma unroll
    for (int im = 0; im < 4; im++)
#pragma unroll
        for (int r = 0; r < 4; r++) {
            float v = psum[im][r];
            v += __shfl_xor(v, 1);
            v += __shfl_xor(v, 2);
            v += __shfl_xor(v, 4);
            v += __shfl_xor(v, 8);
            if (lrow == 0) {
                int gi = bm * 128 + wr * 64 + im * 16 + quad * 4 + r;
                atomicAdd(&lsum[b * SEQ + gi], v);
            }
        }
}

// =====================================================================
// PV GEMM: 64x64, BK=64, single-buffer 2-barrier (R7 structure), full
// causal K per block. Balanced causal XCD map: XCD x owns bm in
// {x, 31-x, x+8, 23-x} per batch -> 66 ktile-sum/XCD (was 1.5x skewed).
// Direct fp32 store with 1/l + FUSED attnF emission (writer bn==kt%8).
// =====================================================================
__global__ __launch_bounds__(256, 4) void gemm_pv_kernel(
    const u16* __restrict__ attnH, const u16* __restrict__ vT,
    float* __restrict__ out, float* __restrict__ attnF,
    const float* __restrict__ lsum)
{
    const int lda = SEQ, ldb = SEQ, ldc = DIM;
    // flat grid 1024: xcd = n&7, i = n>>3 in [0,128): bn = i&7, g = i>>3:
    // b = g>>2, q = g&3, bm = [x, 31-x, x+8, 23-x][q]  (balanced causal)
    int n = blockIdx.x;
    int xcd = n & 7, i = n >> 3;
    int bn = i & 7;
    int g = i >> 3;
    int b = g >> 2, q = g & 3;
    int bm = (q == 0) ? xcd : (q == 1) ? 31 - xcd : (q == 2) ? xcd + 8 : 23 - xcd;

    __shared__ __align__(16) u16 As[64 * 64];
    __shared__ __align__(16) u16 Bs[64 * 64];

    int t = threadIdx.x, wave = t >> 6, lane = t & 63;
    int wr = wave >> 1, wc = wave & 1;
    int lrow = lane & 15, quad = lane >> 4;
    int srow = lane >> 3, sc = lane & 7;

    const u16* Ab = attnH + (size_t)b * SEQ * SEQ + (size_t)(bm * 64) * lda;
    const u16* Bb = vT + (size_t)b * DIM * SEQ + (size_t)(bn * 64) * ldb;
    float* attnFb = attnF + (size_t)b * SEQ * SEQ;

    // zero-fill the fully-masked attnF tiles owned by this bn
    {
        int r = t >> 2, c4 = t & 3;
        float4 z = (float4){0.f, 0.f, 0.f, 0.f};
        for (int kt = bm + 1; kt < 32; ++kt)
            if ((kt & 7) == bn) {
                float* dst = attnFb + (size_t)(bm * 64 + r) * SEQ + kt * 64 + c4 * 16;
                ((float4*)dst)[0] = z; ((float4*)dst)[1] = z;
                ((float4*)dst)[2] = z; ((float4*)dst)[3] = z;
            }
    }

    float4e acc[2][2];
#pragma unroll
    for (int i2 = 0; i2 < 2; i2++)
#pragma unroll
        for (int j2 = 0; j2 < 2; j2++) acc[i2][j2] = (float4e){0.f, 0.f, 0.f, 0.f};

    for (int kt = 0; kt <= bm; ++kt) {
        int k0 = kt << 6;
        __syncthreads();
#pragma unroll
        for (int h = 0; h < 2; ++h) {
            int q2 = wave * 2 + h;
            int row = q2 * 8 + srow;
            int c = sc ^ (row & 7);
            gl_lds16(Ab + (size_t)row * lda + k0 + c * 8, &As[q2 * 512]);
            gl_lds16(Bb + (size_t)row * ldb + k0 + c * 8, &Bs[q2 * 512]);
        }
        __syncthreads();
#pragma unroll
        for (int s = 0; s < 2; ++s) {
            short8 af[2], bfr[2];
#pragma unroll
            for (int im = 0; im < 2; im++) {
                int R = wr * 32 + im * 16 + lrow;
                af[im] = *(const short8*)&As[R * 64 + (((s * 4 + quad) ^ (R & 7)) * 8)];
            }
#pragma unroll
            for (int in = 0; in < 2; in++) {
                int R = wc * 32 + in * 16 + lrow;
                bfr[in] = *(const short8*)&Bs[R * 64 + (((s * 4 + quad) ^ (R & 7)) * 8)];
            }
#pragma unroll
            for (int im = 0; im < 2; im++)
#pragma unroll
                for (int in = 0; in < 2; in++)
                    acc[im][in] = __builtin_amdgcn_mfma_f32_16x16x32_bf16(af[im], bfr[in], acc[im][in], 0, 0, 0);
        }
        // fused attnF emission from the staged LDS A-tile (unique writer: bn == kt%8)
        if ((kt & 7) == bn) {
            int r = t >> 2, c4 = t & 3;
            int gi = bm * 64 + r;
            float invl = 1.0f / lsum[b * SEQ + gi];
            const u16* src = &As[r * 64];
            int j0 = c4 * 2;
            ushort8 u0 = *(const ushort8*)&src[(j0 ^ (r & 7)) * 8];
            ushort8 u1 = *(const ushort8*)&src[((j0 + 1) ^ (r & 7)) * 8];
            float* dst = attnFb + (size_t)gi * SEQ + kt * 64 + c4 * 16;
            float4 f0 = {bf2f(u0[0]) * invl, bf2f(u0[1]) * invl, bf2f(u0[2]) * invl, bf2f(u0[3]) * invl};
            float4 f1 = {bf2f(u0[4]) * invl, bf2f(u0[5]) * invl, bf2f(u0[6]) * invl, bf2f(u0[7]) * invl};
            float4 f2 = {bf2f(u1[0]) * invl, bf2f(u1[1]) * invl, bf2f(u1[2]) * invl, bf2f(u1[3]) * invl};
            float4 f3 = {bf2f(u1[4]) * invl, bf2f(u1[5]) * invl, bf2f(u1[6]) * invl, bf2f(u1[7]) * invl};
            ((float4*)dst)[0] = f0; ((float4*)dst)[1] = f1;
            ((float4*)dst)[2] = f2; ((float4*)dst)[3] = f3;
        }
    }

    float* Cb = out + (size_t)b * SEQ * DIM;
#pragma unroll
    for (int im = 0; im < 2; im++)
#pragma unroll
        for (int r = 0; r < 4; r++) {
            int gi = bm * 64 + wr * 32 + im * 16 + quad * 4 + r;
            float invl = 1.0f / lsum[b * SEQ + gi];
#pragma unroll
            for (int in = 0; in < 2; in++) {
                int gd = bn * 64 + wc * 32 + in * 16 + lrow;
                Cb[(size_t)gi * ldc + gd] = acc[im][in][r] * invl;
            }
        }
}

// ---------------- launch ----------------
extern "C" void kernel_launch(void* const* d_in, const int* in_sizes, int n_in,
                              void* d_out, int out_size, void* d_ws, size_t ws_size,
                              hipStream_t stream) {
    (void)in_sizes; (void)n_in; (void)out_size; (void)ws_size;

    const float* x    = (const float*)d_in[0];
    const float* Wq   = (const float*)d_in[1];
    const float* bq   = (const float*)d_in[2];
    const float* Wk   = (const float*)d_in[3];
    const float* bk   = (const float*)d_in[4];
    const float* Wv   = (const float*)d_in[5];
    const float* bv   = (const float*)d_in[6];
    const float* curv = (const float*)d_in[7];
    const float* temp = (const float*)d_in[8];

    float* out   = (float*)d_out;                       // [4][2048][512]
    float* attnF = out + (size_t)NB * SEQ * DIM;        // [4][2048][2048]

    char* ws = (char*)d_ws;
    // layout (bytes), peak 58.95 MB:
    //   0        attnH  33,554,432  (aliases x_bf@0 (8.4M) + Wcat@8388608
    //                                (1.5M) — both dead after QKV)
    //   33554432 qbuf    8,388,608  [8192][512] bf16
    //   41943040 kbuf    8,388,608  [8192][512] bf16
    //   50331648 vT      8,388,608  [4][512][2048] bf16
    //   58720256 qn2r       32,768  raw row-norm sums (f32)
    //   58753024 kn2r       32,768
    //   58785792 lsum       32,768
    //   58818560 qpk        65,536  float2 {proj norm^2, scale}
    //   58884096 kpk        65,536
    u16*   x_bf  = (u16*)(ws + 0);
    u16*   Wcat  = (u16*)(ws + 8388608);
    u16*   attnH = (u16*)(ws + 0);
    u16*   qbuf  = (u16*)(ws + 33554432);
    u16*   kbuf  = (u16*)(ws + 41943040);
    u16*   vT    = (u16*)(ws + 50331648);
    float* qn2r  = (float*)(ws + 58720256);
    float* kn2r  = (float*)(ws + 58753024);
    float* lsum  = (float*)(ws + 58785792);
    float2* qpk  = (float2*)(ws + 58818560);
    float2* kpk  = (float2*)(ws + 58884096);

    // K0: conversions + zero lsum/qn2r/kn2r
    {
        int n_tot = (NB * SEQ * DIM + 3 * DIM * DIM) / 4;
        cvt_all_kernel<<<(n_tot + 255) / 256, 256, 0, stream>>>(
            x, Wq, Wk, Wv, x_bf, Wcat, lsum, qn2r, kn2r);
    }

    // K1: QKV GEMM (M=8192, N=1536, K=512), XCD-swizzled flat grid 768
    gemm_qkv_kernel<<<768, 256, 0, stream>>>(
        x_bf, Wcat, qbuf, kbuf, vT, bq, bk, bv, qn2r, kn2r);

    // K1.5: per-row projection scales
    rownorm_kernel<<<NB * SEQ / 256, 256, 0, stream>>>(qn2r, kn2r, qpk, kpk, curv);

    // K2: scores, 8-wave blocks, balanced XCD map, flat grid 1024
    gemm_scores_kernel<<<1024, 512, 0, stream>>>(
        qbuf, kbuf, attnH, lsum, qpk, kpk, curv, temp);

    // K3: PV + fused attnF, balanced XCD map, flat grid 1024
    gemm_pv_kernel<<<1024, 256, 0, stream>>>(
        attnH, vT, out, attnF, lsum);
}